// Round 1
// baseline (68.376 us; speedup 1.0000x reference)
//
#include <hip/hip_runtime.h>

// DAA autoencoder: two masked-reduction layers.
//   layer0: h[b][o]   = min_i ( sel0[o][i] ? x[b][i] : 2.0f )   (t-norm)
//   layer1: out[b][o] = max_i ( sel1[o][i] ? h[b][i] : -1.0f )  (t-conorm)
// B=256, IN=1024, HID=512.
//
// Mapping: thread = batch b (blockDim=256=B), block = OT consecutive output
// nodes. sel addresses are wave-uniform -> scalar loads (s_load_dwordx4).
// x loads are per-thread float4 row streams (L1-mediated). Offset is the
// reduction identity given acc init, so masked edges cost cndmask+min only.

#define BATCH 256

template<int INF, int OT, bool ISMIN>
__global__ __launch_bounds__(BATCH) void daa_layer(
    const float* __restrict__ in, const int* __restrict__ sel,
    float* __restrict__ out, int OUTF)
{
    const int b  = threadIdx.x;
    const int o0 = blockIdx.x * OT;
    const float off = ISMIN ? 2.0f : -1.0f;

    float acc[OT];
#pragma unroll
    for (int u = 0; u < OT; ++u) acc[u] = off;

    const float4* __restrict__ xr = (const float4*)(in + (size_t)b * INF);

#pragma unroll 4
    for (int i = 0; i < INF / 4; ++i) {
        const float4 xv = xr[i];
#pragma unroll
        for (int u = 0; u < OT; ++u) {
            const int4 sv = ((const int4*)(sel + (size_t)(o0 + u) * INF))[i];
            // sel==1 -> take x, else reduction identity (2.0 for min, -1 for max)
            const float v0 = sv.x ? xv.x : off;
            const float v1 = sv.y ? xv.y : off;
            const float v2 = sv.z ? xv.z : off;
            const float v3 = sv.w ? xv.w : off;
            if (ISMIN) {
                acc[u] = fminf(acc[u], fminf(fminf(v0, v1), fminf(v2, v3)));
            } else {
                acc[u] = fmaxf(acc[u], fmaxf(fmaxf(v0, v1), fmaxf(v2, v3)));
            }
        }
    }

#pragma unroll
    for (int u = 0; u < OT; ++u)
        out[(size_t)b * OUTF + (o0 + u)] = acc[u];
}

extern "C" void kernel_launch(void* const* d_in, const int* in_sizes, int n_in,
                              void* d_out, int out_size, void* d_ws, size_t ws_size,
                              hipStream_t stream) {
    const float* x    = (const float*)d_in[0];  // [256,1024] f32
    const int*   sel0 = (const int*)d_in[1];    // [512,1024] i32
    const int*   sel1 = (const int*)d_in[2];    // [1024,512] i32
    float* out = (float*)d_out;                 // [256,1024] f32
    float* h   = (float*)d_ws;                  // [256,512]  f32 scratch (512 KB)

    // layer 0: 1024 -> 512, min. OT=2 -> 256 blocks (1/CU), traffic ~268 MB L2.
    daa_layer<1024, 2, true ><<<512 / 2,  BATCH, 0, stream>>>(x, sel0, h, 512);
    // layer 1: 512 -> 1024, max. OT=4 -> 256 blocks, traffic ~134 MB L2.
    daa_layer< 512, 4, false><<<1024 / 4, BATCH, 0, stream>>>(h, sel1, out, 1024);
}